// Round 1
// baseline (205.812 us; speedup 1.0000x reference)
//
#include <hip/hip_runtime.h>

// out[p*128 + c] = in[p*128 + max(c - mag, 0)],  mag = (int)(15.f * frame_value)
// p in [0, 1024*1024), c in [0, 128). Pure memory-bound channel shift.

__global__ __launch_bounds__(256) void translation_shift_kernel(
    const float* __restrict__ in,
    const float* __restrict__ fv,   // frame_value scalar (device)
    float* __restrict__ out,
    long long n4)                   // total float4 outputs
{
    // mag computed exactly as reference: f32 multiply then truncate toward zero.
    const int mag = (int)(15.0f * fv[0]);

    long long i = (long long)blockIdx.x * blockDim.x + threadIdx.x;
    const long long stride = (long long)gridDim.x * blockDim.x;

    for (; i < n4; i += stride) {
        // 32 float4 per 128-channel row
        const int c4 = ((int)(i & 31)) << 2;          // starting channel of this float4
        const long long base = (i >> 5) << 7;         // p * 128

        float4 v;
        int s0 = c4 + 0 - mag;
        int s1 = c4 + 1 - mag;
        int s2 = c4 + 2 - mag;
        int s3 = c4 + 3 - mag;
        v.x = in[base + (s0 > 0 ? s0 : 0)];
        v.y = in[base + (s1 > 0 ? s1 : 0)];
        v.z = in[base + (s2 > 0 ? s2 : 0)];
        v.w = in[base + (s3 > 0 ? s3 : 0)];

        reinterpret_cast<float4*>(out)[i] = v;
    }
}

extern "C" void kernel_launch(void* const* d_in, const int* in_sizes, int n_in,
                              void* d_out, int out_size, void* d_ws, size_t ws_size,
                              hipStream_t stream) {
    const float* x  = (const float*)d_in[0];   // [1,1024,1024,128] f32
    const float* fv = (const float*)d_in[1];   // scalar f32
    float* out = (float*)d_out;

    const long long n4 = (long long)out_size / 4;   // 33,554,432 float4s

    const int block = 256;
    // Memory-bound: cap grid at ~8 blocks/CU * 256 CUs and grid-stride.
    long long want = (n4 + block - 1) / block;
    int grid = (int)(want < 2048 ? want : 2048);

    translation_shift_kernel<<<grid, block, 0, stream>>>(x, fv, out, n4);
}

// Round 2
// 198.799 us; speedup vs baseline: 1.0353x; 1.0353x over previous
//
#include <hip/hip_runtime.h>

// out[p*128 + c] = in[p*128 + max(c - mag, 0)], mag = (int)(15.f * frame_value), mag in [0,14].
// Strategy: aligned global->LDS staging (dwordx4 via global_load_lds), then the
// misaligned channel shift is resolved with cheap clamped LDS scalar reads.

#define BLOCK 256
#define F4_PER_CHUNK 1024   // 32 rows * 32 float4/row
#define STAGES 4            // F4_PER_CHUNK / BLOCK

__global__ __launch_bounds__(BLOCK) void translation_shift_lds(
    const float4* __restrict__ in4,
    const float* __restrict__ fv,
    float4* __restrict__ out4,
    int nChunks)
{
    __shared__ float lds[32 * 128];   // 16 KiB: 32 rows x 128 channels

    // mag exactly as reference: f32 multiply then truncation toward zero.
    const int mag = (int)(15.0f * fv[0]);
    const int t = (int)threadIdx.x;

    for (int chunk = blockIdx.x; chunk < nChunks; chunk += gridDim.x) {
        const long long base4 = (long long)chunk * F4_PER_CHUNK;

        // ---- stage: aligned 16B/lane direct-to-LDS (wave-uniform base + lane*16) ----
        #pragma unroll
        for (int s = 0; s < STAGES; ++s) {
            const int idx = t + s * BLOCK;
            __builtin_amdgcn_global_load_lds(
                (const __attribute__((address_space(1))) void*)(in4 + base4 + idx),
                (__attribute__((address_space(3))) void*)(&lds[idx * 4]),
                16, 0, 0);
        }
        __syncthreads();   // compiler drains vmcnt(0) before the barrier

        // ---- shifted read from LDS, aligned float4 store to global ----
        #pragma unroll
        for (int s = 0; s < STAGES; ++s) {
            const int idx = t + s * BLOCK;
            const int row = idx >> 5;          // 0..31 within the chunk
            const int c4  = (idx & 31) << 2;   // starting channel 0..124
            const float* __restrict__ r = &lds[row << 7];

            const int s0 = c4 + 0 - mag;
            const int s1 = c4 + 1 - mag;
            const int s2 = c4 + 2 - mag;
            const int s3 = c4 + 3 - mag;

            float4 v;
            v.x = r[s0 > 0 ? s0 : 0];
            v.y = r[s1 > 0 ? s1 : 0];
            v.z = r[s2 > 0 ? s2 : 0];
            v.w = r[s3 > 0 ? s3 : 0];

            out4[base4 + idx] = v;
        }
        __syncthreads();   // protect LDS before next chunk's staging
    }
}

extern "C" void kernel_launch(void* const* d_in, const int* in_sizes, int n_in,
                              void* d_out, int out_size, void* d_ws, size_t ws_size,
                              hipStream_t stream) {
    const float4* x4 = (const float4*)d_in[0];   // [1,1024,1024,128] f32
    const float*  fv = (const float*)d_in[1];    // scalar f32
    float4* out4 = (float4*)d_out;

    const long long n4 = (long long)out_size / 4;          // 33,554,432 float4s
    const int nChunks  = (int)(n4 / F4_PER_CHUNK);         // 32,768 (exact)

    // 2048 blocks = 8 blocks/CU * 256 CUs, all co-resident at 16 KiB LDS.
    const int grid = nChunks < 2048 ? nChunks : 2048;

    translation_shift_lds<<<grid, BLOCK, 0, stream>>>(x4, fv, out4, nChunks);
}